// Round 16
// baseline (322.906 us; speedup 1.0000x reference)
//
#include <hip/hip_runtime.h>

typedef unsigned short ushort_t;
typedef unsigned int uint32;
typedef __bf16 bf16x8 __attribute__((ext_vector_type(8)));
typedef float f32x4 __attribute__((ext_vector_type(4)));
typedef ushort_t us4 __attribute__((ext_vector_type(4)));

#define D_    256
#define NH_   8
#define HD_   32
#define NQ_   900
#define BS_   8
#define TOK_  7200
#define NV_   21760
#define QP_   928     // padded KV/Q length for attention (29*32)
#define DFFN_ 1024

__device__ __forceinline__ ushort_t f2bf(float x) {
    union { float f; uint32 u; } v; v.f = x;
    uint32 r = v.u + 0x7FFFu + ((v.u >> 16) & 1u);
    return (ushort_t)(r >> 16);
}
__device__ __forceinline__ float bf2f(ushort_t h) {
    union { uint32 u; float f; } v; v.u = ((uint32)h) << 16;
    return v.f;
}
__device__ __forceinline__ int imin(int a, int b) { return a < b ? a : b; }
__device__ __forceinline__ int imax(int a, int b) { return a > b ? a : b; }

// ---------------------------------------------------------------- fused weight cvt
__global__ __launch_bounds__(256) void cvtall_k(
    const float* __restrict__ s0, const float* __restrict__ s1, const float* __restrict__ s2,
    const float* __restrict__ s3, const float* __restrict__ s4, const float* __restrict__ s5,
    const float* __restrict__ s6, const float* __restrict__ s7, const float* __restrict__ s8,
    const float* __restrict__ s9, const float* __restrict__ s10, ushort_t* __restrict__ dst,
    const float* __restrict__ bq, const float* __restrict__ bk, const float* __restrict__ bv,
    const float* __restrict__ boff, const float* __restrict__ battn,
    float* __restrict__ bias_qkv, float* __restrict__ bias_ol) {
    int tid = threadIdx.x;
    if (blockIdx.x == 0) {
        bias_qkv[tid] = bq[tid];
        bias_qkv[256 + tid] = bk[tid];
        bias_qkv[512 + tid] = bv[tid];
        bias_ol[tid] = boff[tid];
        if (tid < 128) bias_ol[256 + tid] = battn[tid];
    }
    int id = blockIdx.x * 256 + tid;   // float4 id, 0..319487
    const float* s; int off;
    if      (id <  16384) { s = s0;  off = id; }
    else if (id <  32768) { s = s1;  off = id - 16384; }
    else if (id <  49152) { s = s2;  off = id - 32768; }
    else if (id <  65536) { s = s3;  off = id - 49152; }
    else if (id <  81920) { s = s4;  off = id - 65536; }
    else if (id <  98304) { s = s5;  off = id - 81920; }
    else if (id < 114688) { s = s6;  off = id - 98304; }
    else if (id < 122880) { s = s7;  off = id - 114688; }
    else if (id < 188416) { s = s8;  off = id - 122880; }
    else if (id < 253952) { s = s9;  off = id - 188416; }
    else                  { s = s10; off = id - 253952; }
    f32x4 v = *(const f32x4*)(s + (size_t)off * 4);
    us4 t;
#pragma unroll
    for (int e = 0; e < 4; e++) t[e] = f2bf(v[e]);
    *(us4*)(dst + (size_t)id * 4) = t;
}

// ---------------------------------------------------------------- rmsnorm (vectorized)
__global__ __launch_bounds__(256) void rms_k(const float* __restrict__ x,
                                             const float* __restrict__ pos,
                                             const float* __restrict__ wn,
                                             ushort_t* __restrict__ xn_out,
                                             ushort_t* __restrict__ qk_out) {
    const int r = blockIdx.x * 4 + (threadIdx.x >> 6);
    const int lane = threadIdx.x & 63;
    const size_t base = (size_t)r * D_ + lane * 4;
    f32x4 v = *(const f32x4*)(x + base);
    float ss = v[0] * v[0] + v[1] * v[1] + v[2] * v[2] + v[3] * v[3];
#pragma unroll
    for (int o = 32; o; o >>= 1) ss += __shfl_xor(ss, o, 64);
    float sc = rsqrtf(ss * (1.f / 256.f) + 1e-6f);
    f32x4 wv = *(const f32x4*)(wn + lane * 4);
    if (xn_out) {
        us4 t;
#pragma unroll
        for (int e = 0; e < 4; e++) t[e] = f2bf(v[e] * sc * wv[e]);
        *(us4*)(xn_out + base) = t;
    }
    if (qk_out) {
        f32x4 p = *(const f32x4*)(pos + base);
        us4 t;
#pragma unroll
        for (int e = 0; e < 4; e++) t[e] = f2bf(v[e] * sc * wv[e] + p[e]);
        *(us4*)(qk_out + base) = t;
    }
}

// ---------------------------------------------------------------- LDS-staged GEMM (r5 depth-1)
enum { EPI_RESID, EPI_QKV, EPI_OFFLOG };

template <int EPI, bool AF32, int BM, int BN, int WGM, int WGN, int TK>
__global__ __launch_bounds__(WGM * WGN * 64) void gemm2_k(
    const void* __restrict__ Ap, const void* __restrict__ Ap2,
    const ushort_t* __restrict__ Wp,
    const float* __restrict__ bias, void* __restrict__ outp, void* __restrict__ outp2,
    void* __restrict__ outp3, int M, int N, int swz,
    const float* __restrict__ resid, const float* __restrict__ ls, float scale) {
    constexpr int THREADS = WGM * WGN * 64;
    constexpr int NK  = TK / 32;
    constexpr int LDK = 40;
    constexpr int WR  = BM / WGM, WC = BN / WGN;
    constexpr int FM  = WR / 16,  FN = WC / 16;
    constexpr int ACH = AF32 ? (BM * 32 / 4 / THREADS) : (BM * 32 / 8 / THREADS);
    constexpr int BCH = BN * 32 / 8 / THREADS;

    __shared__ __align__(16) ushort_t As[2][BM * LDK];
    __shared__ __align__(16) ushort_t Bs[2][BN * LDK];

    const int tid = threadIdx.x, l = tid & 63, w = tid >> 6;
    const int wm = w % WGM, wn = w / WGM;
    int by = blockIdx.y;
    if (swz) { int cpx = gridDim.y >> 3; by = (by & 7) * cpx + (by >> 3); }
    const int m0 = by * BM, n0 = blockIdx.x * BN;
    const int lr = l & 15, lkb = (l >> 4) * 8;

    const void* Asel = (EPI == EPI_QKV && n0 >= 512) ? Ap2 : Ap;
    const ushort_t* Ab = (const ushort_t*)Asel;
    const float*    Af = (const float*)Asel;

    int aRow[ACH], aK[ACH], bRow[BCH], bK[BCH];
#pragma unroll
    for (int ch = 0; ch < ACH; ch++) {
        int cid = ch * THREADS + tid;
        if constexpr (AF32) { aRow[ch] = cid >> 3; aK[ch] = (cid & 7) * 4; }
        else                { aRow[ch] = cid >> 2; aK[ch] = (cid & 3) * 8; }
    }
#pragma unroll
    for (int ch = 0; ch < BCH; ch++) {
        int cid = ch * THREADS + tid;
        bRow[ch] = cid >> 2; bK[ch] = (cid & 3) * 8;
    }
    int aGRow[ACH];
#pragma unroll
    for (int ch = 0; ch < ACH; ch++) aGRow[ch] = imin(m0 + aRow[ch], M - 1);

    f32x4  aSTf[AF32 ? ACH : 1];
    bf16x8 aSTb[AF32 ? 1 : ACH];
    bf16x8 bST[BCH];

    auto load_regs = [&](int kt) {
        const int k0 = kt * 32;
#pragma unroll
        for (int ch = 0; ch < ACH; ch++) {
            if constexpr (AF32)
                aSTf[ch] = *(const f32x4*)(Af + (size_t)aGRow[ch] * TK + k0 + aK[ch]);
            else
                aSTb[ch] = *(const bf16x8*)(Ab + (size_t)aGRow[ch] * TK + k0 + aK[ch]);
        }
#pragma unroll
        for (int ch = 0; ch < BCH; ch++)
            bST[ch] = *(const bf16x8*)(Wp + (size_t)(n0 + bRow[ch]) * TK + k0 + bK[ch]);
    };
    auto write_lds = [&](int buf) {
#pragma unroll
        for (int ch = 0; ch < ACH; ch++) {
            if constexpr (AF32) {
                us4 t;
#pragma unroll
                for (int e = 0; e < 4; e++) t[e] = f2bf(aSTf[ch][e]);
                *(us4*)&As[buf][aRow[ch] * LDK + aK[ch]] = t;
            } else {
                *(bf16x8*)&As[buf][aRow[ch] * LDK + aK[ch]] = aSTb[ch];
            }
        }
#pragma unroll
        for (int ch = 0; ch < BCH; ch++)
            *(bf16x8*)&Bs[buf][bRow[ch] * LDK + bK[ch]] = bST[ch];
    };

    f32x4 acc[FM][FN];
#pragma unroll
    for (int i = 0; i < FM; i++)
#pragma unroll
        for (int j = 0; j < FN; j++) acc[i][j] = f32x4{0.f, 0.f, 0.f, 0.f};

    load_regs(0);
    write_lds(0);
    __syncthreads();

    for (int kt = 0; kt < NK; ++kt) {
        const int c = kt & 1;
        if (kt + 1 < NK) load_regs(kt + 1);

        bf16x8 af[FM], bf_[FN];
#pragma unroll
        for (int i = 0; i < FM; i++)
            af[i] = *(const bf16x8*)&As[c][(wm * WR + i * 16 + lr) * LDK + lkb];
#pragma unroll
        for (int j = 0; j < FN; j++)
            bf_[j] = *(const bf16x8*)&Bs[c][(wn * WC + j * 16 + lr) * LDK + lkb];
#pragma unroll
        for (int i = 0; i < FM; i++)
#pragma unroll
            for (int j = 0; j < FN; j++)
                acc[i][j] = __builtin_amdgcn_mfma_f32_16x16x32_bf16(af[i], bf_[j], acc[i][j], 0, 0, 0);

        if (kt + 1 < NK) write_lds(c ^ 1);
        __syncthreads();
    }

#pragma unroll
    for (int i = 0; i < FM; i++)
#pragma unroll
        for (int j = 0; j < FN; j++) {
            int col = n0 + wn * WC + j * 16 + lr;
            float bvv = bias[col];
#pragma unroll
            for (int e = 0; e < 4; e++) {
                int row = m0 + wm * WR + i * 16 + (l >> 4) * 4 + e;
                if (row >= M) continue;
                float v = acc[i][j][e] + bvv;
                if constexpr (EPI == EPI_RESID) {
                    size_t idx = (size_t)row * N + col;
                    ((float*)outp)[idx] = resid[idx] + ls[col] * v;
                } else if constexpr (EPI == EPI_QKV) {
                    int c2 = col & 255;
                    int q = row >> 3, bb = row & 7, h = c2 >> 5, hd = c2 & 31;
                    if (col < 256) {
                        ((ushort_t*)outp)[((bb * NH_ + h) * QP_ + q) * HD_ + hd] = f2bf(v * scale);
                    } else if (col < 512) {
                        ((ushort_t*)outp2)[((bb * NH_ + h) * QP_ + q) * HD_ + hd] = f2bf(v);
                    } else {
                        ((ushort_t*)outp3)[((bb * NH_ + h) * HD_ + hd) * QP_ + q] = f2bf(v);
                    }
                } else if constexpr (EPI == EPI_OFFLOG) {
                    if (col < 256) ((float*)outp)[(size_t)row * 256 + col] = v;
                    else           ((float*)outp2)[(size_t)row * 128 + col - 256] = v;
                }
            }
        }
}

// ---------------------------------------------------------------- val GEMM (r13: BK=64)
__global__ __launch_bounds__(512) void gemm4_k(
    const float* __restrict__ Af, const ushort_t* __restrict__ Wp,
    const float* __restrict__ bias, ushort_t* __restrict__ outp, int swz) {
    constexpr int TK = 256, NK = 4, LDK = 72;
    __shared__ __align__(16) ushort_t As[2][64 * LDK];

    const int tid = threadIdx.x, l = tid & 63, w = tid >> 6;   // w = 0..7
    int by = blockIdx.y;
    if (swz) { int cpx = gridDim.y >> 3; by = (by & 7) * cpx + (by >> 3); }
    const int m0 = by * 64;
    const int lr = l & 15, g = l >> 4, lkb = g * 8;

    const int aRow = tid >> 3, aK = (tid & 7) * 4;
    const float* aPtr = Af + (size_t)(m0 + aRow) * TK + aK;
    f32x4 aST0, aST1;
    auto loadA = [&](int kt) {
        aST0 = *(const f32x4*)(aPtr + kt * 64);
        aST1 = *(const f32x4*)(aPtr + kt * 64 + 32);
    };
    auto writeA = [&](int buf) {
        us4 t0, t1;
#pragma unroll
        for (int e = 0; e < 4; e++) { t0[e] = f2bf(aST0[e]); t1[e] = f2bf(aST1[e]); }
        *(us4*)&As[buf][aRow * LDK + aK] = t0;
        *(us4*)&As[buf][aRow * LDK + 32 + aK] = t1;
    };

    const ushort_t* bPtr0 = Wp + (size_t)(w * 32 + lr) * TK + lkb;
    const ushort_t* bPtr1 = Wp + (size_t)(w * 32 + 16 + lr) * TK + lkb;

    f32x4 acc[4][2];
#pragma unroll
    for (int i = 0; i < 4; i++)
#pragma unroll
        for (int j = 0; j < 2; j++) acc[i][j] = f32x4{0.f, 0.f, 0.f, 0.f};

    bf16x8 bC[2][2], bN[2][2];
    loadA(0);
#pragma unroll
    for (int kk = 0; kk < 2; kk++) {
        bC[kk][0] = *(const bf16x8*)(bPtr0 + kk * 32);
        bC[kk][1] = *(const bf16x8*)(bPtr1 + kk * 32);
    }
    writeA(0);
    __syncthreads();

    for (int kt = 0; kt < NK; ++kt) {
        const int c = kt & 1;
        if (kt + 1 < NK) {
            loadA(kt + 1);
#pragma unroll
            for (int kk = 0; kk < 2; kk++) {
                bN[kk][0] = *(const bf16x8*)(bPtr0 + (kt + 1) * 64 + kk * 32);
                bN[kk][1] = *(const bf16x8*)(bPtr1 + (kt + 1) * 64 + kk * 32);
            }
        }
#pragma unroll
        for (int kk = 0; kk < 2; kk++) {
            bf16x8 af[4];
#pragma unroll
            for (int i = 0; i < 4; i++)
                af[i] = *(const bf16x8*)&As[c][(i * 16 + lr) * LDK + kk * 32 + lkb];
#pragma unroll
            for (int i = 0; i < 4; i++) {
                acc[i][0] = __builtin_amdgcn_mfma_f32_16x16x32_bf16(af[i], bC[kk][0], acc[i][0], 0, 0, 0);
                acc[i][1] = __builtin_amdgcn_mfma_f32_16x16x32_bf16(af[i], bC[kk][1], acc[i][1], 0, 0, 0);
            }
        }
        if (kt + 1 < NK) writeA(c ^ 1);
        __syncthreads();
#pragma unroll
        for (int kk = 0; kk < 2; kk++) {
            bC[kk][0] = bN[kk][0];
            bC[kk][1] = bN[kk][1];
        }
    }

#pragma unroll
    for (int i = 0; i < 4; i++)
#pragma unroll
        for (int j = 0; j < 2; j++) {
            int col = w * 32 + j * 16 + lr;
            float bvv = bias[col];
            int h = col >> 5, d = col & 31;
#pragma unroll
            for (int e = 0; e < 4; e++) {
                int row = m0 + i * 16 + g * 4 + e;
                int vv = row >> 3, bb = row & 7;
                outp[(((size_t)(bb * NH_ + h)) * NV_ + vv) * HD_ + d] = f2bf(acc[i][j][e] + bvv);
            }
        }
}

// ---------------------------------------------------------------- FFN gate+up (r16: BK=64, A-only LDS)
// A (bf16) staged in LDS with BK=64 -> 4 barrier events (was 8 with 30 KB A+G+U);
// Wg/Wu frags direct from L2 (1 MB resident) with kt-ahead register prefetch.
// BM=64, BN=128, 4 waves (1m x 4n), grid (8, ceil(M/64)).
__global__ __launch_bounds__(256) void ffn2_k(
    const ushort_t* __restrict__ Ap, const ushort_t* __restrict__ Wg,
    const ushort_t* __restrict__ Wu, const float* __restrict__ bgp,
    const float* __restrict__ bup, ushort_t* __restrict__ outp, int M) {
    constexpr int TK = 256, NK = 4, LDK = 72;
    __shared__ __align__(16) ushort_t As[2][64 * LDK];

    const int tid = threadIdx.x, l = tid & 63, w = tid >> 6;   // w = 0..3
    const int m0 = blockIdx.y * 64, n0 = blockIdx.x * 128;
    const int lr = l & 15, g = l >> 4, lkb = g * 8;

    // A staging: 64 rows x 64 k bf16 per kt; 4 threads/row, 16 elems each
    const int aRow = tid >> 2, aK = (tid & 3) * 16;
    const int aGRow = imin(m0 + aRow, M - 1);
    const ushort_t* aPtr = Ap + (size_t)aGRow * TK + aK;
    bf16x8 aST0, aST1;
    auto loadA = [&](int kt) {
        aST0 = *(const bf16x8*)(aPtr + kt * 64);
        aST1 = *(const bf16x8*)(aPtr + kt * 64 + 8);
    };
    auto writeA = [&](int buf) {
        *(bf16x8*)&As[buf][aRow * LDK + aK] = aST0;
        *(bf16x8*)&As[buf][aRow * LDK + aK + 8] = aST1;
    };

    const ushort_t* gP0 = Wg + (size_t)(n0 + w * 32 + lr) * TK + lkb;
    const ushort_t* gP1 = Wg + (size_t)(n0 + w * 32 + 16 + lr) * TK + lkb;
    const ushort_t* uP0 = Wu + (size_t)(n0 + w * 32 + lr) * TK + lkb;
    const ushort_t* uP1 = Wu + (size_t)(n0 + w * 32 + 16 + lr) * TK + lkb;

    f32x4 accG[4][2], accU[4][2];
#pragma unroll
    for (int i = 0; i < 4; i++)
#pragma unroll
        for (int j = 0; j < 2; j++) { accG[i][j] = f32x4{0,0,0,0}; accU[i][j] = f32x4{0,0,0,0}; }

    bf16x8 gC[2][2], uC[2][2], gN[2][2], uN[2][2];   // [kk][col]
    loadA(0);
#pragma unroll
    for (int kk = 0; kk < 2; kk++) {
        gC[kk][0] = *(const bf16x8*)(gP0 + kk * 32);
        gC[kk][1] = *(const bf16x8*)(gP1 + kk * 32);
        uC[kk][0] = *(const bf16x8*)(uP0 + kk * 32);
        uC[kk][1] = *(const bf16x8*)(uP1 + kk * 32);
    }
    writeA(0);
    __syncthreads();

    for (int kt = 0; kt < NK; ++kt) {
        const int c = kt & 1;
        if (kt + 1 < NK) {
            loadA(kt + 1);
#pragma unroll
            for (int kk = 0; kk < 2; kk++) {
                gN[kk][0] = *(const bf16x8*)(gP0 + (kt + 1) * 64 + kk * 32);
                gN[kk][1] = *(const bf16x8*)(gP1 + (kt + 1) * 64 + kk * 32);
                uN[kk][0] = *(const bf16x8*)(uP0 + (kt + 1) * 64 + kk * 32);
                uN[kk][1] = *(const bf16x8*)(uP1 + (kt + 1) * 64 + kk * 32);
            }
        }
#pragma unroll
        for (int kk = 0; kk < 2; kk++) {
            bf16x8 af[4];
#pragma unroll
            for (int i = 0; i < 4; i++)
                af[i] = *(const bf16x8*)&As[c][(i * 16 + lr) * LDK + kk * 32 + lkb];
#pragma unroll
            for (int i = 0; i < 4; i++) {
                accG[i][0] = __builtin_amdgcn_mfma_f32_16x16x32_bf16(af[i], gC[kk][0], accG[i][0], 0, 0, 0);
                accG[i][1] = __builtin_amdgcn_mfma_f32_16x16x32_bf16(af[i], gC[kk][1], accG[i][1], 0, 0, 0);
                accU[i][0] = __builtin_amdgcn_mfma_f32_16x16x32_bf16(af[i], uC[kk][0], accU[i][0], 0, 0, 0);
                accU[i][1] = __builtin_amdgcn_mfma_f32_16x16x32_bf16(af[i], uC[kk][1], accU[i][1], 0, 0, 0);
            }
        }
        if (kt + 1 < NK) writeA(c ^ 1);
        __syncthreads();
#pragma unroll
        for (int kk = 0; kk < 2; kk++) {
            gC[kk][0] = gN[kk][0]; gC[kk][1] = gN[kk][1];
            uC[kk][0] = uN[kk][0]; uC[kk][1] = uN[kk][1];
        }
    }

#pragma unroll
    for (int i = 0; i < 4; i++)
#pragma unroll
        for (int j = 0; j < 2; j++) {
            int col = n0 + w * 32 + j * 16 + lr;
            float bg_ = bgp[col], bu_ = bup[col];
#pragma unroll
            for (int e = 0; e < 4; e++) {
                int row = m0 + i * 16 + g * 4 + e;
                if (row >= M) continue;
                float gg = accG[i][j][e] + bg_;
                float uu = accU[i][j][e] + bu_;
                float s = gg / (1.f + __expf(-gg));
                outp[(size_t)row * DFFN_ + col] = f2bf(s * uu);
            }
        }
}

// ---------------------------------------------------------------- FFN down-proj (r16: K=1024, BK=64)
// NK=16 barrier events (was 32 in the gemm2 TK=1024 path). A-only LDS, Wf (524 KB,
// L2-resident) in registers with kt-ahead prefetch. Epilogue = residual add (f32).
__global__ __launch_bounds__(256) void down_k(
    const ushort_t* __restrict__ Ap, const ushort_t* __restrict__ Wf,
    const float* __restrict__ bias, float* __restrict__ outp, int M,
    const float* __restrict__ resid, const float* __restrict__ ls) {
    constexpr int TK = 1024, NK = 16, LDK = 72;
    __shared__ __align__(16) ushort_t As[2][64 * LDK];

    const int tid = threadIdx.x, l = tid & 63, w = tid >> 6;   // w = 0..3
    const int m0 = blockIdx.y * 64, n0 = blockIdx.x * 128;
    const int lr = l & 15, g = l >> 4, lkb = g * 8;

    const int aRow = tid >> 2, aK = (tid & 3) * 16;
    const int aGRow = imin(m0 + aRow, M - 1);
    const ushort_t* aPtr = Ap + (size_t)aGRow * TK + aK;
    bf16x8 aST0, aST1;
    auto loadA = [&](int kt) {
        aST0 = *(const bf16x8*)(aPtr + kt * 64);
        aST1 = *(const bf16x8*)(aPtr + kt * 64 + 8);
    };
    auto writeA = [&](int buf) {
        *(bf16x8*)&As[buf][aRow * LDK + aK] = aST0;
        *(bf16x8*)&As[buf][aRow * LDK + aK + 8] = aST1;
    };

    const ushort_t* bP0 = Wf + (size_t)(n0 + w * 32 + lr) * TK + lkb;
    const ushort_t* bP1 = Wf + (size_t)(n0 + w * 32 + 16 + lr) * TK + lkb;

    f32x4 acc[4][2];
#pragma unroll
    for (int i = 0; i < 4; i++)
#pragma unroll
        for (int j = 0; j < 2; j++) acc[i][j] = f32x4{0.f, 0.f, 0.f, 0.f};

    bf16x8 bC[2][2], bN[2][2];
    loadA(0);
#pragma unroll
    for (int kk = 0; kk < 2; kk++) {
        bC[kk][0] = *(const bf16x8*)(bP0 + kk * 32);
        bC[kk][1] = *(const bf16x8*)(bP1 + kk * 32);
    }
    writeA(0);
    __syncthreads();

    for (int kt = 0; kt < NK; ++kt) {
        const int c = kt & 1;
        if (kt + 1 < NK) {
            loadA(kt + 1);
#pragma unroll
            for (int kk = 0; kk < 2; kk++) {
                bN[kk][0] = *(const bf16x8*)(bP0 + (kt + 1) * 64 + kk * 32);
                bN[kk][1] = *(const bf16x8*)(bP1 + (kt + 1) * 64 + kk * 32);
            }
        }
#pragma unroll
        for (int kk = 0; kk < 2; kk++) {
            bf16x8 af[4];
#pragma unroll
            for (int i = 0; i < 4; i++)
                af[i] = *(const bf16x8*)&As[c][(i * 16 + lr) * LDK + kk * 32 + lkb];
#pragma unroll
            for (int i = 0; i < 4; i++) {
                acc[i][0] = __builtin_amdgcn_mfma_f32_16x16x32_bf16(af[i], bC[kk][0], acc[i][0], 0, 0, 0);
                acc[i][1] = __builtin_amdgcn_mfma_f32_16x16x32_bf16(af[i], bC[kk][1], acc[i][1], 0, 0, 0);
            }
        }
        if (kt + 1 < NK) writeA(c ^ 1);
        __syncthreads();
#pragma unroll
        for (int kk = 0; kk < 2; kk++) {
            bC[kk][0] = bN[kk][0];
            bC[kk][1] = bN[kk][1];
        }
    }

#pragma unroll
    for (int i = 0; i < 4; i++)
#pragma unroll
        for (int j = 0; j < 2; j++) {
            int col = n0 + w * 32 + j * 16 + lr;
            float bvv = bias[col], lsc = ls[col];
#pragma unroll
            for (int e = 0; e < 4; e++) {
                int row = m0 + i * 16 + g * 4 + e;
                if (row >= M) continue;
                size_t idx = (size_t)row * 256 + col;
                outp[idx] = resid[idx] + lsc * (acc[i][j][e] + bvv);
            }
        }
}

// ---------------------------------------------------------------- flash self-attention
__global__ __launch_bounds__(256) void attn2_k(const ushort_t* __restrict__ qb,
                                               const ushort_t* __restrict__ kb,
                                               const ushort_t* __restrict__ vtb,
                                               ushort_t* __restrict__ sab) {
    __shared__ __align__(16) ushort_t Pl[4][16 * 40];
    const int tid = threadIdx.x, l = tid & 63, w = tid >> 6;
    const int bh = blockIdx.y, b = bh >> 3, h = bh & 7;
    const int q0 = (blockIdx.x * 4 + w) * 16;
    if (q0 >= NQ_) return;                       // no __syncthreads below: safe
    const int q = l & 15, g = l >> 4;
    ushort_t* Pw = &Pl[w][0];

    const bf16x8 qf = *(const bf16x8*)(qb + ((size_t)bh * QP_ + q0 + q) * HD_ + g * 8);
    const ushort_t* kbase = kb + (size_t)bh * QP_ * HD_;
    const ushort_t* vbase = vtb + (size_t)bh * HD_ * QP_;

    f32x4 O0 = {0.f, 0.f, 0.f, 0.f}, O1 = {0.f, 0.f, 0.f, 0.f};
    float m = -1e30f, sl = 0.f;

    auto ldk = [&](int t, int u) {
        return *(const bf16x8*)(kbase + (size_t)(t * 32 + u * 16 + q) * HD_ + g * 8);
    };
    auto ldv = [&](int t, int dh) {
        return *(const bf16x8*)(vbase + (size_t)(dh * 16 + q) * QP_ + t * 32 + g * 8);
    };
    bf16x8 kA = ldk(0, 0), kB = ldk(0, 1), v0 = ldv(0, 0), v1 = ldv(0, 1);

    for (int t = 0; t < 29; ++t) {
        bf16x8 nkA, nkB, nv0, nv1;
        if (t < 28) { nkA = ldk(t + 1, 0); nkB = ldk(t + 1, 1); nv0 = ldv(t + 1, 0); nv1 = ldv(t + 1, 1); }
        const f32x4 z = {0.f, 0.f, 0.f, 0.f};
        f32x4 sA = __builtin_amdgcn_mfma_f32_16x16x32_bf16(kA, qf, z, 0, 0, 0);
        f32x4 sB = __builtin_amdgcn_mfma_f32_16x16x32_bf16(kB, qf, z, 0, 0, 0);
        if (t == 28) {   // keys 896..927: mask >= 900
            int k0 = 896 + g * 4;
#pragma unroll
            for (int e = 0; e < 4; e++) {
                if (k0 + e >= NQ_)      sA[e] = -1e30f;
                if (k0 + 16 + e >= NQ_) sB[e] = -1e30f;
            }
        }
        float tm = fmaxf(fmaxf(fmaxf(sA[0], sA[1]), fmaxf(sA[2], sA[3])),
                         fmaxf(fmaxf(sB[0], sB[1]), fmaxf(sB[2], sB[3])));
        tm = fmaxf(tm, __shfl_xor(tm, 16, 64));
        tm = fmaxf(tm, __shfl_xor(tm, 32, 64));
        float mn = fmaxf(m, tm);
        float r = exp2f(m - mn);
        m = mn;
#pragma unroll
        for (int e = 0; e < 4; e++) { O0[e] *= r; O1[e] *= r; }
        float pA[4], pB[4], ps = 0.f;
#pragma unroll
        for (int e = 0; e < 4; e++) {
            pA[e] = exp2f(sA[e] - m); pB[e] = exp2f(sB[e] - m);
            ps += pA[e] + pB[e];
        }
        sl = sl * r + ps;
        uint32 a0, a1, b0, b1;
        asm("v_cvt_pk_bf16_f32 %0, %1, %2" : "=v"(a0) : "v"(pA[0]), "v"(pA[1]));
        asm("v_cvt_pk_bf16_f32 %0, %1, %2" : "=v"(a1) : "v"(pA[2]), "v"(pA[3]));
        asm("v_cvt_pk_bf16_f32 %0, %1, %2" : "=v"(b0) : "v"(pB[0]), "v"(pB[1]));
        asm("v_cvt_pk_bf16_f32 %0, %1, %2" : "=v"(b1) : "v"(pB[2]), "v"(pB[3]));
        { uint2 tt; tt.x = a0; tt.y = a1; *(uint2*)(Pw + q * 40 + g * 4) = tt; }
        { uint2 tt; tt.x = b0; tt.y = b1; *(uint2*)(Pw + q * 40 + 16 + g * 4) = tt; }
        bf16x8 pf = *(const bf16x8*)(Pw + q * 40 + g * 8);
        O0 = __builtin_amdgcn_mfma_f32_16x16x32_bf16(v0, pf, O0, 0, 0, 0);
        O1 = __builtin_amdgcn_mfma_f32_16x16x32_bf16(v1, pf, O1, 0, 0, 0);
        kA = nkA; kB = nkB; v0 = nv0; v1 = nv1;
    }

    sl += __shfl_xor(sl, 16, 64);
    sl += __shfl_xor(sl, 32, 64);
    float inv = 1.f / sl;
    int row_q = q0 + q;
    if (row_q < NQ_) {
        ushort_t* op = sab + ((size_t)row_q * BS_ + b) * D_ + h * HD_ + g * 4;
#pragma unroll
        for (int dh = 0; dh < 2; dh++) {
            f32x4 Ov = dh ? O1 : O0;
            float e0 = Ov[0] * inv, e1 = Ov[1] * inv, e2 = Ov[2] * inv, e3 = Ov[3] * inv;
            uint32 w0, w1;
            asm("v_cvt_pk_bf16_f32 %0, %1, %2" : "=v"(w0) : "v"(e0), "v"(e1));
            asm("v_cvt_pk_bf16_f32 %0, %1, %2" : "=v"(w1) : "v"(e2), "v"(e3));
            *(uint32*)(op + dh * 16) = w0;
            *(uint32*)(op + dh * 16 + 2) = w1;
        }
    }
}

// ---------------------------------------------------------------- deformable sampling
__global__ __launch_bounds__(256) void deform_k(
    const float* __restrict__ offb, const float* __restrict__ logb,
    const float* __restrict__ refpts, const int* __restrict__ shapes,
    const int* __restrict__ lsi, const ushort_t* __restrict__ val,
    ushort_t* __restrict__ ca) {
    __shared__ float off_l[256];
    __shared__ float attw[128];
    const int r = blockIdx.x;
    const int b = r & 7;
    const int tid = threadIdx.x;

    off_l[tid] = offb[(size_t)r * 256 + tid];
    if (tid < 128) {
        float lg = logb[(size_t)r * 128 + tid];
        float m = lg;
#pragma unroll
        for (int o = 1; o < 16; o <<= 1) m = fmaxf(m, __shfl_xor(m, o, 16));
        float e = __expf(lg - m);
        float s = e;
#pragma unroll
        for (int o = 1; o < 16; o <<= 1) s += __shfl_xor(s, o, 16);
        attw[tid] = e / s;
    }
    __syncthreads();

    const int h = tid >> 5, d = tid & 31;
    const ushort_t* vb = val + ((size_t)(b * NH_ + h)) * NV_ * HD_;
    float acc = 0.f;
#pragma unroll
    for (int lvl = 0; lvl < 4; lvl++) {
        const int H = shapes[lvl * 2], W = shapes[lvl * 2 + 1];
        const int base = lsi[lvl];
        const float refx = refpts[(r * 4 + lvl) * 2];
        const float refy = refpts[(r * 4 + lvl) * 2 + 1];
#pragma unroll
        for (int p = 0; p < 4; p++) {
            int oi = ((h * 4 + lvl) * 4 + p) * 2;
            float x = (refx + off_l[oi] / (float)W) * (float)W - 0.5f;
            float y = (refy + off_l[oi + 1] / (float)H) * (float)H - 0.5f;
            float x0 = floorf(x), y0 = floorf(y);
            float fx = x - x0, fy = y - y0;
            int ix = (int)x0, iy = (int)y0;
            float sval = 0.f;
#pragma unroll
            for (int dy = 0; dy <= 1; dy++)
#pragma unroll
                for (int dx = 0; dx <= 1; dx++) {
                    int xi = ix + dx, yi = iy + dy;
                    float wq = (dx ? fx : 1.f - fx) * (dy ? fy : 1.f - fy);
                    if (xi < 0 || xi >= W || yi < 0 || yi >= H) wq = 0.f;
                    int cx = imin(imax(xi, 0), W - 1), cy = imin(imax(yi, 0), H - 1);
                    float vv = bf2f(vb[(size_t)(base + cy * W + cx) * HD_ + d]);
                    sval += wq * vv;
                }
            acc += attw[h * 16 + lvl * 4 + p] * sval;
        }
    }
    ca[(size_t)r * 256 + tid] = f2bf(acc);
}

// ---------------------------------------------------------------- launch
extern "C" void kernel_launch(void* const* d_in, const int* in_sizes, int n_in,
                              void* d_out, int out_size, void* d_ws, size_t ws_size,
                              hipStream_t stream) {
    (void)in_sizes; (void)n_in; (void)out_size; (void)ws_size;
    const float* tgt    = (const float*)d_in[0];
    const float* qpos   = (const float*)d_in[1];
    const float* refp   = (const float*)d_in[2];
    const float* mem    = (const float*)d_in[3];
    const int*   shapes = (const int*)d_in[4];
    const int*   lsi    = (const int*)d_in[5];
    const float* wnsa   = (const float*)d_in[6];
    const float* wnca   = (const float*)d_in[7];
    const float* wnffn  = (const float*)d_in[8];
    const float* lssa   = (const float*)d_in[9];
    const float* lsca   = (const float*)d_in[10];
    const float* lsffn  = (const float*)d_in[11];
    const float* Wq = (const float*)d_in[12];
    const float* Wk = (const float*)d_in[13];
    const float* Wv = (const float*)d_in[14];
    const float* bq = (const float*)d_in[15];
    const float* bk = (const float*)d_in[16];
    const float* bvv = (const float*)d_in[17];
    const float* Wo_sa = (const float*)d_in[18];
    const float* bo_sa = (const float*)d_in[19];
    const float* Wv_proj = (const float*)d_in[20];
    const float* bv_proj = (const float*)d_in[21];
    const float* W_off = (const float*)d_in[22];
    const float* b_off = (const float*)d_in[23];
    const float* W_attn = (const float*)d_in[24];
    const float* b_attn = (const float*)d_in[25];
    const float* W_out = (const float*)d_in[26];
    const float* bo_ca = (const float*)d_in[27];
    const float* Wg = (const float*)d_in[28];
    const float* bg = (const float*)d_in[29];
    const float* Wu = (const float*)d_in[30];
    const float* bu = (const float*)d_in[31];
    const float* Wf = (const float*)d_in[32];
    const float* bff = (const float*)d_in[33];

    char* ws = (char*)d_ws;
    size_t o = 0;
    auto alloc = [&](size_t b) { size_t c = o; o += (b + 255) & ~(size_t)255; return c; };

    // NOTE: weight segments must stay contiguous & in this order for cvtall_k.
    const size_t wq_o = alloc(65536 * 2), wk_o = alloc(65536 * 2), wv_o = alloc(65536 * 2);
    const size_t wosa_o = alloc(65536 * 2), wvp_o = alloc(65536 * 2), wout_o = alloc(65536 * 2);
    const size_t woff_o = alloc(65536 * 2), wattn_o = alloc(32768 * 2);
    const size_t wg_o = alloc(262144 * 2), wu_o = alloc(262144 * 2), wf_o = alloc(262144 * 2);
    const size_t bqkv_o = alloc(768 * 4), bol_o = alloc(384 * 4);
    const size_t xnsa_o = alloc((size_t)TOK_ * D_ * 2);
    const size_t qksa_o = alloc((size_t)TOK_ * D_ * 2);
    const size_t qkvBytes = (size_t)BS_ * NH_ * QP_ * HD_ * 2;
    const size_t qb_o = alloc(qkvBytes);
    const size_t kb_o = alloc(qkvBytes);
    const size_t vt_o = alloc(qkvBytes + 512);
    const size_t sa_o = alloc((size_t)TOK_ * D_ * 2);
    const size_t tgt1_o = alloc((size_t)TOK_ * D_ * 4);
    const size_t qca_o = alloc((size_t)TOK_ * D_ * 2);
    const size_t offb_o = alloc((size_t)TOK_ * 256 * 4);
    const size_t logit_o = alloc((size_t)TOK_ * 128 * 4);
    const size_t ca_o = alloc((size_t)TOK_ * D_ * 2);
    const size_t tgt2_o = alloc((size_t)TOK_ * D_ * 4);
    const size_t val_o = alloc((size_t)NV_ * BS_ * D_ * 2);
    // FFN h buffer aliases the (dead-after-sampling) val region:
    const size_t h_o  = val_o;
    const size_t xn3_o = h_o + (size_t)TOK_ * DFFN_ * 2;

    dim3 blk(256);
    cvtall_k<<<dim3(319488 / 256), blk, 0, stream>>>(
        Wq, Wk, Wv, Wo_sa, Wv_proj, W_out, W_off, W_attn, Wg, Wu, Wf,
        (ushort_t*)(ws + wq_o),
        bq, bk, bvv, b_off, b_attn, (float*)(ws + bqkv_o), (float*)(ws + bol_o));

    // No vt-pad memset: PV multiplies pad cols (900..927) by P == exact 0,
    // and the pad bytes are always finite -> 0 * finite = 0.

    // ---- phase A: self-attention ----
    rms_k<<<dim3(TOK_ / 4), blk, 0, stream>>>(tgt, qpos, wnsa,
                                              (ushort_t*)(ws + xnsa_o), (ushort_t*)(ws + qksa_o));
    const float QSC = 0.25503321550239915f;  // log2(e)/sqrt(32): exp2-domain scores
    gemm2_k<EPI_QKV, false, 64, 128, 2, 2, 256><<<dim3(6, 113), blk, 0, stream>>>(
        ws + qksa_o, ws + xnsa_o, (ushort_t*)(ws + wq_o), (const float*)(ws + bqkv_o),
        ws + qb_o, ws + kb_o, ws + vt_o, TOK_, 768, 0, nullptr, nullptr, QSC);
    attn2_k<<<dim3(15, 64), blk, 0, stream>>>((ushort_t*)(ws + qb_o), (ushort_t*)(ws + kb_o),
                                              (ushort_t*)(ws + vt_o), (ushort_t*)(ws + sa_o));
    gemm2_k<EPI_RESID, false, 64, 128, 2, 2, 256><<<dim3(2, 113), blk, 0, stream>>>(
        ws + sa_o, nullptr, (ushort_t*)(ws + wosa_o), bo_sa, ws + tgt1_o, nullptr, nullptr,
        TOK_, 256, 0, tgt, lssa, 1.f);

    // ---- phase B: deformable cross-attention ----
    rms_k<<<dim3(TOK_ / 4), blk, 0, stream>>>((const float*)(ws + tgt1_o), qpos, wnca,
                                              nullptr, (ushort_t*)(ws + qca_o));
    gemm2_k<EPI_OFFLOG, false, 64, 128, 2, 2, 256><<<dim3(3, 113), blk, 0, stream>>>(
        ws + qca_o, nullptr, (ushort_t*)(ws + woff_o), (const float*)(ws + bol_o),
        ws + offb_o, ws + logit_o, nullptr, TOK_, 384, 0, nullptr, nullptr, 1.f);
    gemm4_k<<<dim3(1, 2720), dim3(512), 0, stream>>>(
        mem, (ushort_t*)(ws + wvp_o), bv_proj, (ushort_t*)(ws + val_o), 1);
    deform_k<<<dim3(TOK_), blk, 0, stream>>>(
        (const float*)(ws + offb_o), (const float*)(ws + logit_o), refp, shapes, lsi,
        (ushort_t*)(ws + val_o), (ushort_t*)(ws + ca_o));
    gemm2_k<EPI_RESID, false, 64, 128, 2, 2, 256><<<dim3(2, 113), blk, 0, stream>>>(
        ws + ca_o, nullptr, (ushort_t*)(ws + wout_o), bo_ca, ws + tgt2_o, nullptr, nullptr,
        TOK_, 256, 0, (const float*)(ws + tgt1_o), lsca, 1.f);

    // ---- phase C: FFN ----
    rms_k<<<dim3(TOK_ / 4), blk, 0, stream>>>((const float*)(ws + tgt2_o), nullptr, wnffn,
                                              (ushort_t*)(ws + xn3_o), nullptr);
    ffn2_k<<<dim3(8, 113), blk, 0, stream>>>(
        (const ushort_t*)(ws + xn3_o), (const ushort_t*)(ws + wg_o),
        (const ushort_t*)(ws + wu_o), bg, bu, (ushort_t*)(ws + h_o), TOK_);
    down_k<<<dim3(2, 113), blk, 0, stream>>>(
        (const ushort_t*)(ws + h_o), (const ushort_t*)(ws + wf_o), bff,
        (float*)d_out, TOK_, (const float*)(ws + tgt2_o), lsffn);
}

// Round 17
// 315.072 us; speedup vs baseline: 1.0249x; 1.0249x over previous
//
#include <hip/hip_runtime.h>

typedef unsigned short ushort_t;
typedef unsigned int uint32;
typedef __bf16 bf16x8 __attribute__((ext_vector_type(8)));
typedef float f32x4 __attribute__((ext_vector_type(4)));
typedef ushort_t us4 __attribute__((ext_vector_type(4)));

#define D_    256
#define NH_   8
#define HD_   32
#define NQ_   900
#define BS_   8
#define TOK_  7200
#define NV_   21760
#define QP_   928     // padded KV/Q length for attention (29*32)
#define DFFN_ 1024

__device__ __forceinline__ ushort_t f2bf(float x) {
    union { float f; uint32 u; } v; v.f = x;
    uint32 r = v.u + 0x7FFFu + ((v.u >> 16) & 1u);
    return (ushort_t)(r >> 16);
}
__device__ __forceinline__ float bf2f(ushort_t h) {
    union { uint32 u; float f; } v; v.u = ((uint32)h) << 16;
    return v.f;
}
__device__ __forceinline__ int imin(int a, int b) { return a < b ? a : b; }
__device__ __forceinline__ int imax(int a, int b) { return a > b ? a : b; }

// ---------------------------------------------------------------- fused weight cvt
__global__ __launch_bounds__(256) void cvtall_k(
    const float* __restrict__ s0, const float* __restrict__ s1, const float* __restrict__ s2,
    const float* __restrict__ s3, const float* __restrict__ s4, const float* __restrict__ s5,
    const float* __restrict__ s6, const float* __restrict__ s7, const float* __restrict__ s8,
    const float* __restrict__ s9, const float* __restrict__ s10, ushort_t* __restrict__ dst,
    const float* __restrict__ bq, const float* __restrict__ bk, const float* __restrict__ bv,
    const float* __restrict__ boff, const float* __restrict__ battn,
    float* __restrict__ bias_qkv, float* __restrict__ bias_ol) {
    int tid = threadIdx.x;
    if (blockIdx.x == 0) {
        bias_qkv[tid] = bq[tid];
        bias_qkv[256 + tid] = bk[tid];
        bias_qkv[512 + tid] = bv[tid];
        bias_ol[tid] = boff[tid];
        if (tid < 128) bias_ol[256 + tid] = battn[tid];
    }
    int id = blockIdx.x * 256 + tid;   // float4 id, 0..319487
    const float* s; int off;
    if      (id <  16384) { s = s0;  off = id; }
    else if (id <  32768) { s = s1;  off = id - 16384; }
    else if (id <  49152) { s = s2;  off = id - 32768; }
    else if (id <  65536) { s = s3;  off = id - 49152; }
    else if (id <  81920) { s = s4;  off = id - 65536; }
    else if (id <  98304) { s = s5;  off = id - 81920; }
    else if (id < 114688) { s = s6;  off = id - 98304; }
    else if (id < 122880) { s = s7;  off = id - 114688; }
    else if (id < 188416) { s = s8;  off = id - 122880; }
    else if (id < 253952) { s = s9;  off = id - 188416; }
    else                  { s = s10; off = id - 253952; }
    f32x4 v = *(const f32x4*)(s + (size_t)off * 4);
    us4 t;
#pragma unroll
    for (int e = 0; e < 4; e++) t[e] = f2bf(v[e]);
    *(us4*)(dst + (size_t)id * 4) = t;
}

// ---------------------------------------------------------------- rmsnorm (vectorized)
__global__ __launch_bounds__(256) void rms_k(const float* __restrict__ x,
                                             const float* __restrict__ pos,
                                             const float* __restrict__ wn,
                                             ushort_t* __restrict__ xn_out,
                                             ushort_t* __restrict__ qk_out) {
    const int r = blockIdx.x * 4 + (threadIdx.x >> 6);
    const int lane = threadIdx.x & 63;
    const size_t base = (size_t)r * D_ + lane * 4;
    f32x4 v = *(const f32x4*)(x + base);
    float ss = v[0] * v[0] + v[1] * v[1] + v[2] * v[2] + v[3] * v[3];
#pragma unroll
    for (int o = 32; o; o >>= 1) ss += __shfl_xor(ss, o, 64);
    float sc = rsqrtf(ss * (1.f / 256.f) + 1e-6f);
    f32x4 wv = *(const f32x4*)(wn + lane * 4);
    if (xn_out) {
        us4 t;
#pragma unroll
        for (int e = 0; e < 4; e++) t[e] = f2bf(v[e] * sc * wv[e]);
        *(us4*)(xn_out + base) = t;
    }
    if (qk_out) {
        f32x4 p = *(const f32x4*)(pos + base);
        us4 t;
#pragma unroll
        for (int e = 0; e < 4; e++) t[e] = f2bf(v[e] * sc * wv[e] + p[e]);
        *(us4*)(qk_out + base) = t;
    }
}

// ---------------------------------------------------------------- LDS-staged GEMM (r5 depth-1)
enum { EPI_RESID, EPI_OFFLOG };

template <int EPI, int BM, int BN, int WGM, int WGN, int TK>
__global__ __launch_bounds__(WGM * WGN * 64) void gemm2_k(
    const ushort_t* __restrict__ Ab, const ushort_t* __restrict__ Wp,
    const float* __restrict__ bias, void* __restrict__ outp, void* __restrict__ outp2,
    int M, int N,
    const float* __restrict__ resid, const float* __restrict__ ls) {
    constexpr int THREADS = WGM * WGN * 64;
    constexpr int NK  = TK / 32;
    constexpr int LDK = 40;
    constexpr int WR  = BM / WGM, WC = BN / WGN;
    constexpr int FM  = WR / 16,  FN = WC / 16;
    constexpr int ACH = BM * 32 / 8 / THREADS;
    constexpr int BCH = BN * 32 / 8 / THREADS;

    __shared__ __align__(16) ushort_t As[2][BM * LDK];
    __shared__ __align__(16) ushort_t Bs[2][BN * LDK];

    const int tid = threadIdx.x, l = tid & 63, w = tid >> 6;
    const int wm = w % WGM, wn = w / WGM;
    const int m0 = blockIdx.y * BM, n0 = blockIdx.x * BN;
    const int lr = l & 15, lkb = (l >> 4) * 8;

    int aRow[ACH], aK[ACH], bRow[BCH], bK[BCH];
#pragma unroll
    for (int ch = 0; ch < ACH; ch++) {
        int cid = ch * THREADS + tid;
        aRow[ch] = cid >> 2; aK[ch] = (cid & 3) * 8;
    }
#pragma unroll
    for (int ch = 0; ch < BCH; ch++) {
        int cid = ch * THREADS + tid;
        bRow[ch] = cid >> 2; bK[ch] = (cid & 3) * 8;
    }
    int aGRow[ACH];
#pragma unroll
    for (int ch = 0; ch < ACH; ch++) aGRow[ch] = imin(m0 + aRow[ch], M - 1);

    bf16x8 aSTb[ACH];
    bf16x8 bST[BCH];

    auto load_regs = [&](int kt) {
        const int k0 = kt * 32;
#pragma unroll
        for (int ch = 0; ch < ACH; ch++)
            aSTb[ch] = *(const bf16x8*)(Ab + (size_t)aGRow[ch] * TK + k0 + aK[ch]);
#pragma unroll
        for (int ch = 0; ch < BCH; ch++)
            bST[ch] = *(const bf16x8*)(Wp + (size_t)(n0 + bRow[ch]) * TK + k0 + bK[ch]);
    };
    auto write_lds = [&](int buf) {
#pragma unroll
        for (int ch = 0; ch < ACH; ch++)
            *(bf16x8*)&As[buf][aRow[ch] * LDK + aK[ch]] = aSTb[ch];
#pragma unroll
        for (int ch = 0; ch < BCH; ch++)
            *(bf16x8*)&Bs[buf][bRow[ch] * LDK + bK[ch]] = bST[ch];
    };

    f32x4 acc[FM][FN];
#pragma unroll
    for (int i = 0; i < FM; i++)
#pragma unroll
        for (int j = 0; j < FN; j++) acc[i][j] = f32x4{0.f, 0.f, 0.f, 0.f};

    load_regs(0);
    write_lds(0);
    __syncthreads();

    for (int kt = 0; kt < NK; ++kt) {
        const int c = kt & 1;
        if (kt + 1 < NK) load_regs(kt + 1);

        bf16x8 af[FM], bf_[FN];
#pragma unroll
        for (int i = 0; i < FM; i++)
            af[i] = *(const bf16x8*)&As[c][(wm * WR + i * 16 + lr) * LDK + lkb];
#pragma unroll
        for (int j = 0; j < FN; j++)
            bf_[j] = *(const bf16x8*)&Bs[c][(wn * WC + j * 16 + lr) * LDK + lkb];
#pragma unroll
        for (int i = 0; i < FM; i++)
#pragma unroll
            for (int j = 0; j < FN; j++)
                acc[i][j] = __builtin_amdgcn_mfma_f32_16x16x32_bf16(af[i], bf_[j], acc[i][j], 0, 0, 0);

        if (kt + 1 < NK) write_lds(c ^ 1);
        __syncthreads();
    }

#pragma unroll
    for (int i = 0; i < FM; i++)
#pragma unroll
        for (int j = 0; j < FN; j++) {
            int col = n0 + wn * WC + j * 16 + lr;
            float bvv = bias[col];
#pragma unroll
            for (int e = 0; e < 4; e++) {
                int row = m0 + wm * WR + i * 16 + (l >> 4) * 4 + e;
                if (row >= M) continue;
                float v = acc[i][j][e] + bvv;
                if constexpr (EPI == EPI_RESID) {
                    size_t idx = (size_t)row * N + col;
                    ((float*)outp)[idx] = resid[idx] + ls[col] * v;
                } else {   // EPI_OFFLOG
                    if (col < 256) ((float*)outp)[(size_t)row * 256 + col] = v;
                    else           ((float*)outp2)[(size_t)row * 128 + col - 256] = v;
                }
            }
        }
}

// ---------------------------------------------------------------- fused QKV + val GEMM (r17)
// Grid-partitioned heterogeneous launch (m114 co-scheduling): both roles are
// latency-bound alone; co-resident waves fill each other's HBM/L2 wait slots.
//  blocks 0..677   : QKV projection role (waves 0-3 active; waves 4-7 run
//                    barriers only - uniform, no early-exit/barrier hazard).
//  blocks 678..3397: val GEMM role (r13 gemm4 body, 8 waves, BK=64,
//                    A-only LDS, B from L2, bijective XCD swizzle on 2720).
// Shared 30 KB smem union (QKV: 10.2K A + 20.5K B; val: 18.4K A).
__global__ __launch_bounds__(512) void qkvval_k(
    const ushort_t* __restrict__ qksa, const ushort_t* __restrict__ xnsa,
    const ushort_t* __restrict__ wqkv, const float* __restrict__ bqkv,
    ushort_t* __restrict__ qb, ushort_t* __restrict__ kb, ushort_t* __restrict__ vtb,
    float qscale,
    const float* __restrict__ mem, const ushort_t* __restrict__ wvp,
    const float* __restrict__ bvp, ushort_t* __restrict__ valp) {
    __shared__ __align__(16) char smem[30720];
    const int rid = blockIdx.x;
    const int tid = threadIdx.x, l = tid & 63;
    const int lr = l & 15, g = l >> 4, lkb = g * 8;

    if (rid < 678) {
        // ---------------- QKV role ----------------
        ushort_t* As = (ushort_t*)smem;            // [2][64*40]
        ushort_t* Bs = (ushort_t*)(smem + 10240);  // [2][128*40]
        const bool act = tid < 256;
        const int w4 = (tid >> 6) & 3, wm = w4 & 1, wn = w4 >> 1;
        const int n0 = (rid % 6) * 128, m0 = (rid / 6) * 64;
        const ushort_t* Ab = (n0 >= 512) ? xnsa : qksa;

        const int t8 = tid & 255;
        const int aRow = t8 >> 2, aK = (t8 & 3) * 8;
        const int bRow0 = t8 >> 2, bK0 = (t8 & 3) * 8;
        const int bRow1 = (256 + t8) >> 2, bK1 = ((256 + t8) & 3) * 8;
        const int aGRow = imin(m0 + aRow, TOK_ - 1);

        bf16x8 aST, bST0, bST1;
        f32x4 acc[2][4];
#pragma unroll
        for (int i = 0; i < 2; i++)
#pragma unroll
            for (int j = 0; j < 4; j++) acc[i][j] = f32x4{0.f, 0.f, 0.f, 0.f};

        auto load_regs = [&](int kt) {
            const int k0 = kt * 32;
            aST  = *(const bf16x8*)(Ab + (size_t)aGRow * 256 + k0 + aK);
            bST0 = *(const bf16x8*)(wqkv + (size_t)(n0 + bRow0) * 256 + k0 + bK0);
            bST1 = *(const bf16x8*)(wqkv + (size_t)(n0 + bRow1) * 256 + k0 + bK1);
        };
        auto write_lds = [&](int buf) {
            *(bf16x8*)&As[buf * 2560 + aRow * 40 + aK] = aST;
            *(bf16x8*)&Bs[buf * 5120 + bRow0 * 40 + bK0] = bST0;
            *(bf16x8*)&Bs[buf * 5120 + bRow1 * 40 + bK1] = bST1;
        };

        if (act) { load_regs(0); write_lds(0); }
        __syncthreads();

        for (int kt = 0; kt < 8; ++kt) {
            const int c = kt & 1;
            if (act) {
                if (kt + 1 < 8) load_regs(kt + 1);
                bf16x8 af[2], bf_[4];
#pragma unroll
                for (int i = 0; i < 2; i++)
                    af[i] = *(const bf16x8*)&As[c * 2560 + (wm * 32 + i * 16 + lr) * 40 + lkb];
#pragma unroll
                for (int j = 0; j < 4; j++)
                    bf_[j] = *(const bf16x8*)&Bs[c * 5120 + (wn * 64 + j * 16 + lr) * 40 + lkb];
#pragma unroll
                for (int i = 0; i < 2; i++)
#pragma unroll
                    for (int j = 0; j < 4; j++)
                        acc[i][j] = __builtin_amdgcn_mfma_f32_16x16x32_bf16(af[i], bf_[j], acc[i][j], 0, 0, 0);
                if (kt + 1 < 8) write_lds(c ^ 1);
            }
            __syncthreads();
        }

        if (act) {
#pragma unroll
            for (int i = 0; i < 2; i++)
#pragma unroll
                for (int j = 0; j < 4; j++) {
                    int col = n0 + wn * 64 + j * 16 + lr;
                    float bvv = bqkv[col];
#pragma unroll
                    for (int e = 0; e < 4; e++) {
                        int row = m0 + wm * 32 + i * 16 + g * 4 + e;
                        if (row >= TOK_) continue;
                        float v = acc[i][j][e] + bvv;
                        int c2 = col & 255;
                        int q = row >> 3, bb = row & 7, h = c2 >> 5, hd = c2 & 31;
                        if (col < 256)
                            qb[((bb * NH_ + h) * QP_ + q) * HD_ + hd] = f2bf(v * qscale);
                        else if (col < 512)
                            kb[((bb * NH_ + h) * QP_ + q) * HD_ + hd] = f2bf(v);
                        else
                            vtb[((bb * NH_ + h) * HD_ + hd) * QP_ + q] = f2bf(v);
                    }
                }
        }
        return;
    }

    // ---------------- val role (r13 gemm4 body) ----------------
    {
        constexpr int TK = 256, NK = 4, LDK = 72;
        ushort_t* As = (ushort_t*)smem;   // [2][64*72] = 18432 B

        const int vid = rid - 678;
        const int by = (vid & 7) * 340 + (vid >> 3);   // bijective: 2720 % 8 == 0
        const int w = tid >> 6;                        // 0..7
        const int m0 = by * 64;

        const int aRow = tid >> 3, aK = (tid & 7) * 4;
        const float* aPtr = mem + (size_t)(m0 + aRow) * TK + aK;
        f32x4 aST0, aST1;
        auto loadA = [&](int kt) {
            aST0 = *(const f32x4*)(aPtr + kt * 64);
            aST1 = *(const f32x4*)(aPtr + kt * 64 + 32);
        };
        auto writeA = [&](int buf) {
            us4 t0, t1;
#pragma unroll
            for (int e = 0; e < 4; e++) { t0[e] = f2bf(aST0[e]); t1[e] = f2bf(aST1[e]); }
            *(us4*)&As[buf * 4608 + aRow * LDK + aK] = t0;
            *(us4*)&As[buf * 4608 + aRow * LDK + 32 + aK] = t1;
        };

        const ushort_t* bPtr0 = wvp + (size_t)(w * 32 + lr) * TK + lkb;
        const ushort_t* bPtr1 = wvp + (size_t)(w * 32 + 16 + lr) * TK + lkb;

        f32x4 acc[4][2];
#pragma unroll
        for (int i = 0; i < 4; i++)
#pragma unroll
            for (int j = 0; j < 2; j++) acc[i][j] = f32x4{0.f, 0.f, 0.f, 0.f};

        bf16x8 bC[2][2], bN[2][2];
        loadA(0);
#pragma unroll
        for (int kk = 0; kk < 2; kk++) {
            bC[kk][0] = *(const bf16x8*)(bPtr0 + kk * 32);
            bC[kk][1] = *(const bf16x8*)(bPtr1 + kk * 32);
        }
        writeA(0);
        __syncthreads();

        for (int kt = 0; kt < NK; ++kt) {
            const int c = kt & 1;
            if (kt + 1 < NK) {
                loadA(kt + 1);
#pragma unroll
                for (int kk = 0; kk < 2; kk++) {
                    bN[kk][0] = *(const bf16x8*)(bPtr0 + (kt + 1) * 64 + kk * 32);
                    bN[kk][1] = *(const bf16x8*)(bPtr1 + (kt + 1) * 64 + kk * 32);
                }
            }
#pragma unroll
            for (int kk = 0; kk < 2; kk++) {
                bf16x8 af[4];
#pragma unroll
                for (int i = 0; i < 4; i++)
                    af[i] = *(const bf16x8*)&As[c * 4608 + (i * 16 + lr) * LDK + kk * 32 + lkb];
#pragma unroll
                for (int i = 0; i < 4; i++) {
                    acc[i][0] = __builtin_amdgcn_mfma_f32_16x16x32_bf16(af[i], bC[kk][0], acc[i][0], 0, 0, 0);
                    acc[i][1] = __builtin_amdgcn_mfma_f32_16x16x32_bf16(af[i], bC[kk][1], acc[i][1], 0, 0, 0);
                }
            }
            if (kt + 1 < NK) writeA(c ^ 1);
            __syncthreads();
#pragma unroll
            for (int kk = 0; kk < 2; kk++) {
                bC[kk][0] = bN[kk][0];
                bC[kk][1] = bN[kk][1];
            }
        }

#pragma unroll
        for (int i = 0; i < 4; i++)
#pragma unroll
            for (int j = 0; j < 2; j++) {
                int col = w * 32 + j * 16 + lr;
                float bvv = bvp[col];
                int h = col >> 5, d = col & 31;
#pragma unroll
                for (int e = 0; e < 4; e++) {
                    int row = m0 + i * 16 + g * 4 + e;
                    int vv = row >> 3, bb = row & 7;
                    valp[(((size_t)(bb * NH_ + h)) * NV_ + vv) * HD_ + d] = f2bf(acc[i][j][e] + bvv);
                }
            }
    }
}

// ---------------------------------------------------------------- FFN gate+up (r16: BK=64, A-only LDS)
__global__ __launch_bounds__(256) void ffn2_k(
    const ushort_t* __restrict__ Ap, const ushort_t* __restrict__ Wg,
    const ushort_t* __restrict__ Wu, const float* __restrict__ bgp,
    const float* __restrict__ bup, ushort_t* __restrict__ outp, int M) {
    constexpr int TK = 256, NK = 4, LDK = 72;
    __shared__ __align__(16) ushort_t As[2][64 * LDK];

    const int tid = threadIdx.x, l = tid & 63, w = tid >> 6;   // w = 0..3
    const int m0 = blockIdx.y * 64, n0 = blockIdx.x * 128;
    const int lr = l & 15, g = l >> 4, lkb = g * 8;

    const int aRow = tid >> 2, aK = (tid & 3) * 16;
    const int aGRow = imin(m0 + aRow, M - 1);
    const ushort_t* aPtr = Ap + (size_t)aGRow * TK + aK;
    bf16x8 aST0, aST1;
    auto loadA = [&](int kt) {
        aST0 = *(const bf16x8*)(aPtr + kt * 64);
        aST1 = *(const bf16x8*)(aPtr + kt * 64 + 8);
    };
    auto writeA = [&](int buf) {
        *(bf16x8*)&As[buf][aRow * LDK + aK] = aST0;
        *(bf16x8*)&As[buf][aRow * LDK + aK + 8] = aST1;
    };

    const ushort_t* gP0 = Wg + (size_t)(n0 + w * 32 + lr) * TK + lkb;
    const ushort_t* gP1 = Wg + (size_t)(n0 + w * 32 + 16 + lr) * TK + lkb;
    const ushort_t* uP0 = Wu + (size_t)(n0 + w * 32 + lr) * TK + lkb;
    const ushort_t* uP1 = Wu + (size_t)(n0 + w * 32 + 16 + lr) * TK + lkb;

    f32x4 accG[4][2], accU[4][2];
#pragma unroll
    for (int i = 0; i < 4; i++)
#pragma unroll
        for (int j = 0; j < 2; j++) { accG[i][j] = f32x4{0,0,0,0}; accU[i][j] = f32x4{0,0,0,0}; }

    bf16x8 gC[2][2], uC[2][2], gN[2][2], uN[2][2];   // [kk][col]
    loadA(0);
#pragma unroll
    for (int kk = 0; kk < 2; kk++) {
        gC[kk][0] = *(const bf16x8*)(gP0 + kk * 32);
        gC[kk][1] = *(const bf16x8*)(gP1 + kk * 32);
        uC[kk][0] = *(const bf16x8*)(uP0 + kk * 32);
        uC[kk][1] = *(const bf16x8*)(uP1 + kk * 32);
    }
    writeA(0);
    __syncthreads();

    for (int kt = 0; kt < NK; ++kt) {
        const int c = kt & 1;
        if (kt + 1 < NK) {
            loadA(kt + 1);
#pragma unroll
            for (int kk = 0; kk < 2; kk++) {
                gN[kk][0] = *(const bf16x8*)(gP0 + (kt + 1) * 64 + kk * 32);
                gN[kk][1] = *(const bf16x8*)(gP1 + (kt + 1) * 64 + kk * 32);
                uN[kk][0] = *(const bf16x8*)(uP0 + (kt + 1) * 64 + kk * 32);
                uN[kk][1] = *(const bf16x8*)(uP1 + (kt + 1) * 64 + kk * 32);
            }
        }
#pragma unroll
        for (int kk = 0; kk < 2; kk++) {
            bf16x8 af[4];
#pragma unroll
            for (int i = 0; i < 4; i++)
                af[i] = *(const bf16x8*)&As[c][(i * 16 + lr) * LDK + kk * 32 + lkb];
#pragma unroll
            for (int i = 0; i < 4; i++) {
                accG[i][0] = __builtin_amdgcn_mfma_f32_16x16x32_bf16(af[i], gC[kk][0], accG[i][0], 0, 0, 0);
                accG[i][1] = __builtin_amdgcn_mfma_f32_16x16x32_bf16(af[i], gC[kk][1], accG[i][1], 0, 0, 0);
                accU[i][0] = __builtin_amdgcn_mfma_f32_16x16x32_bf16(af[i], uC[kk][0], accU[i][0], 0, 0, 0);
                accU[i][1] = __builtin_amdgcn_mfma_f32_16x16x32_bf16(af[i], uC[kk][1], accU[i][1], 0, 0, 0);
            }
        }
        if (kt + 1 < NK) writeA(c ^ 1);
        __syncthreads();
#pragma unroll
        for (int kk = 0; kk < 2; kk++) {
            gC[kk][0] = gN[kk][0]; gC[kk][1] = gN[kk][1];
            uC[kk][0] = uN[kk][0]; uC[kk][1] = uN[kk][1];
        }
    }

#pragma unroll
    for (int i = 0; i < 4; i++)
#pragma unroll
        for (int j = 0; j < 2; j++) {
            int col = n0 + w * 32 + j * 16 + lr;
            float bg_ = bgp[col], bu_ = bup[col];
#pragma unroll
            for (int e = 0; e < 4; e++) {
                int row = m0 + i * 16 + g * 4 + e;
                if (row >= M) continue;
                float gg = accG[i][j][e] + bg_;
                float uu = accU[i][j][e] + bu_;
                float s = gg / (1.f + __expf(-gg));
                outp[(size_t)row * DFFN_ + col] = f2bf(s * uu);
            }
        }
}

// ---------------------------------------------------------------- FFN down-proj (r16: K=1024, BK=64)
__global__ __launch_bounds__(256) void down_k(
    const ushort_t* __restrict__ Ap, const ushort_t* __restrict__ Wf,
    const float* __restrict__ bias, float* __restrict__ outp, int M,
    const float* __restrict__ resid, const float* __restrict__ ls) {
    constexpr int TK = 1024, NK = 16, LDK = 72;
    __shared__ __align__(16) ushort_t As[2][64 * LDK];

    const int tid = threadIdx.x, l = tid & 63, w = tid >> 6;   // w = 0..3
    const int m0 = blockIdx.y * 64, n0 = blockIdx.x * 128;
    const int lr = l & 15, g = l >> 4, lkb = g * 8;

    const int aRow = tid >> 2, aK = (tid & 3) * 16;
    const int aGRow = imin(m0 + aRow, M - 1);
    const ushort_t* aPtr = Ap + (size_t)aGRow * TK + aK;
    bf16x8 aST0, aST1;
    auto loadA = [&](int kt) {
        aST0 = *(const bf16x8*)(aPtr + kt * 64);
        aST1 = *(const bf16x8*)(aPtr + kt * 64 + 8);
    };
    auto writeA = [&](int buf) {
        *(bf16x8*)&As[buf][aRow * LDK + aK] = aST0;
        *(bf16x8*)&As[buf][aRow * LDK + aK + 8] = aST1;
    };

    const ushort_t* bP0 = Wf + (size_t)(n0 + w * 32 + lr) * TK + lkb;
    const ushort_t* bP1 = Wf + (size_t)(n0 + w * 32 + 16 + lr) * TK + lkb;

    f32x4 acc[4][2];
#pragma unroll
    for (int i = 0; i < 4; i++)
#pragma unroll
        for (int j = 0; j < 2; j++) acc[i][j] = f32x4{0.f, 0.f, 0.f, 0.f};

    bf16x8 bC[2][2], bN[2][2];
    loadA(0);
#pragma unroll
    for (int kk = 0; kk < 2; kk++) {
        bC[kk][0] = *(const bf16x8*)(bP0 + kk * 32);
        bC[kk][1] = *(const bf16x8*)(bP1 + kk * 32);
    }
    writeA(0);
    __syncthreads();

    for (int kt = 0; kt < NK; ++kt) {
        const int c = kt & 1;
        if (kt + 1 < NK) {
            loadA(kt + 1);
#pragma unroll
            for (int kk = 0; kk < 2; kk++) {
                bN[kk][0] = *(const bf16x8*)(bP0 + (kt + 1) * 64 + kk * 32);
                bN[kk][1] = *(const bf16x8*)(bP1 + (kt + 1) * 64 + kk * 32);
            }
        }
#pragma unroll
        for (int kk = 0; kk < 2; kk++) {
            bf16x8 af[4];
#pragma unroll
            for (int i = 0; i < 4; i++)
                af[i] = *(const bf16x8*)&As[c][(i * 16 + lr) * LDK + kk * 32 + lkb];
#pragma unroll
            for (int i = 0; i < 4; i++) {
                acc[i][0] = __builtin_amdgcn_mfma_f32_16x16x32_bf16(af[i], bC[kk][0], acc[i][0], 0, 0, 0);
                acc[i][1] = __builtin_amdgcn_mfma_f32_16x16x32_bf16(af[i], bC[kk][1], acc[i][1], 0, 0, 0);
            }
        }
        if (kt + 1 < NK) writeA(c ^ 1);
        __syncthreads();
#pragma unroll
        for (int kk = 0; kk < 2; kk++) {
            bC[kk][0] = bN[kk][0];
            bC[kk][1] = bN[kk][1];
        }
    }

#pragma unroll
    for (int i = 0; i < 4; i++)
#pragma unroll
        for (int j = 0; j < 2; j++) {
            int col = n0 + w * 32 + j * 16 + lr;
            float bvv = bias[col], lsc = ls[col];
#pragma unroll
            for (int e = 0; e < 4; e++) {
                int row = m0 + i * 16 + g * 4 + e;
                if (row >= M) continue;
                size_t idx = (size_t)row * 256 + col;
                outp[idx] = resid[idx] + lsc * (acc[i][j][e] + bvv);
            }
        }
}

// ---------------------------------------------------------------- flash self-attention
__global__ __launch_bounds__(256) void attn2_k(const ushort_t* __restrict__ qb,
                                               const ushort_t* __restrict__ kb,
                                               const ushort_t* __restrict__ vtb,
                                               ushort_t* __restrict__ sab) {
    __shared__ __align__(16) ushort_t Pl[4][16 * 40];
    const int tid = threadIdx.x, l = tid & 63, w = tid >> 6;
    const int bh = blockIdx.y, b = bh >> 3, h = bh & 7;
    const int q0 = (blockIdx.x * 4 + w) * 16;
    if (q0 >= NQ_) return;                       // no __syncthreads below: safe
    const int q = l & 15, g = l >> 4;
    ushort_t* Pw = &Pl[w][0];

    const bf16x8 qf = *(const bf16x8*)(qb + ((size_t)bh * QP_ + q0 + q) * HD_ + g * 8);
    const ushort_t* kbase = kb + (size_t)bh * QP_ * HD_;
    const ushort_t* vbase = vtb + (size_t)bh * HD_ * QP_;

    f32x4 O0 = {0.f, 0.f, 0.f, 0.f}, O1 = {0.f, 0.f, 0.f, 0.f};
    float m = -1e30f, sl = 0.f;

    auto ldk = [&](int t, int u) {
        return *(const bf16x8*)(kbase + (size_t)(t * 32 + u * 16 + q) * HD_ + g * 8);
    };
    auto ldv = [&](int t, int dh) {
        return *(const bf16x8*)(vbase + (size_t)(dh * 16 + q) * QP_ + t * 32 + g * 8);
    };
    bf16x8 kA = ldk(0, 0), kB = ldk(0, 1), v0 = ldv(0, 0), v1 = ldv(0, 1);

    for (int t = 0; t < 29; ++t) {
        bf16x8 nkA, nkB, nv0, nv1;
        if (t < 28) { nkA = ldk(t + 1, 0); nkB = ldk(t + 1, 1); nv0 = ldv(t + 1, 0); nv1 = ldv(t + 1, 1); }
        const f32x4 z = {0.f, 0.f, 0.f, 0.f};
        f32x4 sA = __builtin_amdgcn_mfma_f32_16x16x32_bf16(kA, qf, z, 0, 0, 0);
        f32x4 sB = __builtin_amdgcn_mfma_f32_16x16x32_bf16(kB, qf, z, 0, 0, 0);
        if (t == 28) {   // keys 896..927: mask >= 900
            int k0 = 896 + g * 4;
#pragma unroll
            for (int e = 0; e < 4; e++) {
                if (k0 + e >= NQ_)      sA[e] = -1e30f;
                if (k0 + 16 + e >= NQ_) sB[e] = -1e30f;
            }
        }
        float tm = fmaxf(fmaxf(fmaxf(sA[0], sA[1]), fmaxf(sA[2], sA[3])),
                         fmaxf(fmaxf(sB[0], sB[1]), fmaxf(sB[2], sB[3])));
        tm = fmaxf(tm, __shfl_xor(tm, 16, 64));
        tm = fmaxf(tm, __shfl_xor(tm, 32, 64));
        float mn = fmaxf(m, tm);
        float r = exp2f(m - mn);
        m = mn;
#pragma unroll
        for (int e = 0; e < 4; e++) { O0[e] *= r; O1[e] *= r; }
        float pA[4], pB[4], ps = 0.f;
#pragma unroll
        for (int e = 0; e < 4; e++) {
            pA[e] = exp2f(sA[e] - m); pB[e] = exp2f(sB[e] - m);
            ps += pA[e] + pB[e];
        }
        sl = sl * r + ps;
        uint32 a0, a1, b0, b1;
        asm("v_cvt_pk_bf16_f32 %0, %1, %2" : "=v"(a0) : "v"(pA[0]), "v"(pA[1]));
        asm("v_cvt_pk_bf16_f32 %0, %1, %2" : "=v"(a1) : "v"(pA[2]), "v"(pA[3]));
        asm("v_cvt_pk_bf16_f32 %0, %1, %2" : "=v"(b0) : "v"(pB[0]), "v"(pB[1]));
        asm("v_cvt_pk_bf16_f32 %0, %1, %2" : "=v"(b1) : "v"(pB[2]), "v"(pB[3]));
        { uint2 tt; tt.x = a0; tt.y = a1; *(uint2*)(Pw + q * 40 + g * 4) = tt; }
        { uint2 tt; tt.x = b0; tt.y = b1; *(uint2*)(Pw + q * 40 + 16 + g * 4) = tt; }
        bf16x8 pf = *(const bf16x8*)(Pw + q * 40 + g * 8);
        O0 = __builtin_amdgcn_mfma_f32_16x16x32_bf16(v0, pf, O0, 0, 0, 0);
        O1 = __builtin_amdgcn_mfma_f32_16x16x32_bf16(v1, pf, O1, 0, 0, 0);
        kA = nkA; kB = nkB; v0 = nv0; v1 = nv1;
    }

    sl += __shfl_xor(sl, 16, 64);
    sl += __shfl_xor(sl, 32, 64);
    float inv = 1.f / sl;
    int row_q = q0 + q;
    if (row_q < NQ_) {
        ushort_t* op = sab + ((size_t)row_q * BS_ + b) * D_ + h * HD_ + g * 4;
#pragma unroll
        for (int dh = 0; dh < 2; dh++) {
            f32x4 Ov = dh ? O1 : O0;
            float e0 = Ov[0] * inv, e1 = Ov[1] * inv, e2 = Ov[2] * inv, e3 = Ov[3] * inv;
            uint32 w0, w1;
            asm("v_cvt_pk_bf16_f32 %0, %1, %2" : "=v"(w0) : "v"(e0), "v"(e1));
            asm("v_cvt_pk_bf16_f32 %0, %1, %2" : "=v"(w1) : "v"(e2), "v"(e3));
            *(uint32*)(op + dh * 16) = w0;
            *(uint32*)(op + dh * 16 + 2) = w1;
        }
    }
}

// ---------------------------------------------------------------- deformable sampling
__global__ __launch_bounds__(256) void deform_k(
    const float* __restrict__ offb, const float* __restrict__ logb,
    const float* __restrict__ refpts, const int* __restrict__ shapes,
    const int* __restrict__ lsi, const ushort_t* __restrict__ val,
    ushort_t* __restrict__ ca) {
    __shared__ float off_l[256];
    __shared__ float attw[128];
    const int r = blockIdx.x;
    const int b = r & 7;
    const int tid = threadIdx.x;

    off_l[tid] = offb[(size_t)r * 256 + tid];
    if (tid < 128) {
        float lg = logb[(size_t)r * 128 + tid];
        float m = lg;
#pragma unroll
        for (int o = 1; o < 16; o <<= 1) m = fmaxf(m, __shfl_xor(m, o, 16));
        float e = __expf(lg - m);
        float s = e;
#pragma unroll
        for (int o = 1; o < 16; o <<= 1) s += __shfl_xor(s, o, 16);
        attw[tid] = e / s;
    }
    __syncthreads();

    const int h = tid >> 5, d = tid & 31;
    const ushort_t* vb = val + ((size_t)(b * NH_ + h)) * NV_ * HD_;
    float acc = 0.f;
#pragma unroll
    for (int lvl = 0; lvl < 4; lvl++) {
        const int H = shapes[lvl * 2], W = shapes[lvl * 2 + 1];
        const int base = lsi[lvl];
        const float refx = refpts[(r * 4 + lvl) * 2];
        const float refy = refpts[(r * 4 + lvl) * 2 + 1];
#pragma unroll
        for (int p = 0; p < 4; p++) {
            int oi = ((h * 4 + lvl) * 4 + p) * 2;
            float x = (refx + off_l[oi] / (float)W) * (float)W - 0.5f;
            float y = (refy + off_l[oi + 1] / (float)H) * (float)H - 0.5f;
            float x0 = floorf(x), y0 = floorf(y);
            float fx = x - x0, fy = y - y0;
            int ix = (int)x0, iy = (int)y0;
            float sval = 0.f;
#pragma unroll
            for (int dy = 0; dy <= 1; dy++)
#pragma unroll
                for (int dx = 0; dx <= 1; dx++) {
                    int xi = ix + dx, yi = iy + dy;
                    float wq = (dx ? fx : 1.f - fx) * (dy ? fy : 1.f - fy);
                    if (xi < 0 || xi >= W || yi < 0 || yi >= H) wq = 0.f;
                    int cx = imin(imax(xi, 0), W - 1), cy = imin(imax(yi, 0), H - 1);
                    float vv = bf2f(vb[(size_t)(base + cy * W + cx) * HD_ + d]);
                    sval += wq * vv;
                }
            acc += attw[h * 16 + lvl * 4 + p] * sval;
        }
    }
    ca[(size_t)r * 256 + tid] = f2bf(acc);
}

// ---------------------------------------------------------------- launch
extern "C" void kernel_launch(void* const* d_in, const int* in_sizes, int n_in,
                              void* d_out, int out_size, void* d_ws, size_t ws_size,
                              hipStream_t stream) {
    (void)in_sizes; (void)n_in; (void)out_size; (void)ws_size;
    const float* tgt    = (const float*)d_in[0];
    const float* qpos   = (const float*)d_in[1];
    const float* refp   = (const float*)d_in[2];
    const float* mem    = (const float*)d_in[3];
    const int*   shapes = (const int*)d_in[4];
    const int*   lsi    = (const int*)d_in[5];
    const float* wnsa   = (const float*)d_in[6];
    const float* wnca   = (const float*)d_in[7];
    const float* wnffn  = (const float*)d_in[8];
    const float* lssa   = (const float*)d_in[9];
    const float* lsca   = (const float*)d_in[10];
    const float* lsffn  = (const float*)d_in[11];
    const float* Wq = (const float*)d_in[12];
    const float* Wk = (const float*)d_in[13];
    const float* Wv = (const float*)d_in[14];
    const float* bq = (const float*)d_in[15];
    const float* bk = (const float*)d_in[16];
    const float* bvv = (const float*)d_in[17];
    const float* Wo_sa = (const float*)d_in[18];
    const float* bo_sa = (const float*)d_in[19];
    const float* Wv_proj = (const float*)d_in[20];
    const float* bv_proj = (const float*)d_in[21];
    const float* W_off = (const float*)d_in[22];
    const float* b_off = (const float*)d_in[23];
    const float* W_attn = (const float*)d_in[24];
    const float* b_attn = (const float*)d_in[25];
    const float* W_out = (const float*)d_in[26];
    const float* bo_ca = (const float*)d_in[27];
    const float* Wg = (const float*)d_in[28];
    const float* bg = (const float*)d_in[29];
    const float* Wu = (const float*)d_in[30];
    const float* bu = (const float*)d_in[31];
    const float* Wf = (const float*)d_in[32];
    const float* bff = (const float*)d_in[33];

    char* ws = (char*)d_ws;
    size_t o = 0;
    auto alloc = [&](size_t b) { size_t c = o; o += (b + 255) & ~(size_t)255; return c; };

    // NOTE: weight segments must stay contiguous & in this order for cvtall_k.
    const size_t wq_o = alloc(65536 * 2), wk_o = alloc(65536 * 2), wv_o = alloc(65536 * 2);
    const size_t wosa_o = alloc(65536 * 2), wvp_o = alloc(65536 * 2), wout_o = alloc(65536 * 2);
    const size_t woff_o = alloc(65536 * 2), wattn_o = alloc(32768 * 2);
    const size_t wg_o = alloc(262144 * 2), wu_o = alloc(262144 * 2), wf_o = alloc(262144 * 2);
    const size_t bqkv_o = alloc(768 * 4), bol_o = alloc(384 * 4);
    const size_t xnsa_o = alloc((size_t)TOK_ * D_ * 2);
    const size_t qksa_o = alloc((size_t)TOK_ * D_ * 2);
    const size_t qkvBytes = (size_t)BS_ * NH_ * QP_ * HD_ * 2;
    const size_t qb_o = alloc(qkvBytes);
    const size_t kb_o = alloc(qkvBytes);
    const size_t vt_o = alloc(qkvBytes + 512);
    const size_t sa_o = alloc((size_t)TOK_ * D_ * 2);
    const size_t tgt1_o = alloc((size_t)TOK_ * D_ * 4);
    const size_t qca_o = alloc((size_t)TOK_ * D_ * 2);
    const size_t offb_o = alloc((size_t)TOK_ * 256 * 4);
    const size_t logit_o = alloc((size_t)TOK_ * 128 * 4);
    const size_t ca_o = alloc((size_t)TOK_ * D_ * 2);
    const size_t tgt2_o = alloc((size_t)TOK_ * D_ * 4);
    const size_t val_o = alloc((size_t)NV_ * BS_ * D_ * 2);
    // FFN h buffer aliases the (dead-after-sampling) val region:
    const size_t h_o  = val_o;
    const size_t xn3_o = h_o + (size_t)TOK_ * DFFN_ * 2;

    dim3 blk(256);
    cvtall_k<<<dim3(319488 / 256), blk, 0, stream>>>(
        Wq, Wk, Wv, Wo_sa, Wv_proj, W_out, W_off, W_attn, Wg, Wu, Wf,
        (ushort_t*)(ws + wq_o),
        bq, bk, bvv, b_off, b_attn, (float*)(ws + bqkv_o), (float*)(ws + bol_o));

    // No vt-pad memset: PV multiplies pad cols (900..927) by P == exact 0,
    // and the pad bytes are always finite -> 0 * finite = 0.

    // ---- phase A: self-attention (+ co-scheduled val GEMM) ----
    rms_k<<<dim3(TOK_ / 4), blk, 0, stream>>>(tgt, qpos, wnsa,
                                              (ushort_t*)(ws + xnsa_o), (ushort_t*)(ws + qksa_o));
    const float QSC = 0.25503321550239915f;  // log2(e)/sqrt(32): exp2-domain scores
    // fused QKV (678 blocks) + val GEMM (2720 blocks): heterogeneous co-scheduling
    qkvval_k<<<dim3(678 + 2720), dim3(512), 0, stream>>>(
        (const ushort_t*)(ws + qksa_o), (const ushort_t*)(ws + xnsa_o),
        (const ushort_t*)(ws + wq_o), (const float*)(ws + bqkv_o),
        (ushort_t*)(ws + qb_o), (ushort_t*)(ws + kb_o), (ushort_t*)(ws + vt_o), QSC,
        mem, (const ushort_t*)(ws + wvp_o), bv_proj, (ushort_t*)(ws + val_o));
    attn2_k<<<dim3(15, 64), blk, 0, stream>>>((ushort_t*)(ws + qb_o), (ushort_t*)(ws + kb_o),
                                              (ushort_t*)(ws + vt_o), (ushort_t*)(ws + sa_o));
    gemm2_k<EPI_RESID, 64, 128, 2, 2, 256><<<dim3(2, 113), blk, 0, stream>>>(
        (const ushort_t*)(ws + sa_o), (ushort_t*)(ws + wosa_o), bo_sa, ws + tgt1_o, nullptr,
        TOK_, 256, tgt, lssa);

    // ---- phase B: deformable cross-attention ----
    rms_k<<<dim3(TOK_ / 4), blk, 0, stream>>>((const float*)(ws + tgt1_o), qpos, wnca,
                                              nullptr, (ushort_t*)(ws + qca_o));
    gemm2_k<EPI_OFFLOG, 64, 128, 2, 2, 256><<<dim3(3, 113), blk, 0, stream>>>(
        (const ushort_t*)(ws + qca_o), (ushort_t*)(ws + woff_o), (const float*)(ws + bol_o),
        ws + offb_o, ws + logit_o, TOK_, 384, nullptr, nullptr);
    deform_k<<<dim3(TOK_), blk, 0, stream>>>(
        (const float*)(ws + offb_o), (const float*)(ws + logit_o), refp, shapes, lsi,
        (ushort_t*)(ws + val_o), (ushort_t*)(ws + ca_o));
    gemm2_k<EPI_RESID, 64, 128, 2, 2, 256><<<dim3(2, 113), blk, 0, stream>>>(
        (const ushort_t*)(ws + ca_o), (ushort_t*)(ws + wout_o), bo_ca, ws + tgt2_o, nullptr,
        TOK_, 256, (const float*)(ws + tgt1_o), lsca);

    // ---- phase C: FFN ----
    rms_k<<<dim3(TOK_ / 4), blk, 0, stream>>>((const float*)(ws + tgt2_o), nullptr, wnffn,
                                              (ushort_t*)(ws + xn3_o), nullptr);
    ffn2_k<<<dim3(8, 113), blk, 0, stream>>>(
        (const ushort_t*)(ws + xn3_o), (const ushort_t*)(ws + wg_o),
        (const ushort_t*)(ws + wu_o), bg, bu, (ushort_t*)(ws + h_o), TOK_);
    down_k<<<dim3(2, 113), blk, 0, stream>>>(
        (const ushort_t*)(ws + h_o), (const ushort_t*)(ws + wf_o), bff,
        (float*)d_out, TOK_, (const float*)(ws + tgt2_o), lsffn);
}